// Round 12
// baseline (210.690 us; speedup 1.0000x reference)
//
#include <hip/hip_runtime.h>
#include <stdint.h>

#define B_ 32
#define P_ 8732
#define C_ 21
#define TOPK 200
#define TGT 228        // count-search acceptance window center [200,256]
#define TGT0 300       // scatter pre-filter target count (sigma~17: window +-5.9 sigma)
#define CAP 448        // per-task candidate capacity (8.7 sigma above mean)
#define CONF_T 0.01f
#define NMS_T 0.45f
#define NCH2 35        // ceil(P_/256)
#define NT 512         // 8-wave blocks: the only shape that packs (R5/R7/R10 evidence)
#define KV4 5          // slow-path strided load: ceil((P_/4)/NT)
#define NTASK (B_ * C_)

__device__ __forceinline__ uint32_t f2s(float f) {
    uint32_t u = __float_as_uint(f);
    return (u & 0x80000000u) ? ~u : (u | 0x80000000u);
}
__device__ __forceinline__ float s2f(uint32_t s) {
    uint32_t b = (s & 0x80000000u) ? (s & 0x7FFFFFFFu) : ~s;
    return __uint_as_float(b);
}
__device__ __forceinline__ uint32_t keyof(float v) {
    return f2s((v > CONF_T) ? v : -1.0f);
}
__device__ __forceinline__ uint32_t thr0() {
    return f2s(1.0f - (float)TGT0 / (float)P_);   // folds to a constant
}

// conf (B,P,C) f32 -> per-task candidate lists: all (key,~idx) with key >= T0.
// Replaces the full 23.5 MB key transpose: writes only ~1.7 MB of candidates.
__global__ __launch_bounds__(256) void scatter_cands(const float* __restrict__ conf,
                                                     uint32_t* __restrict__ gcnt,
                                                     uint64_t* __restrict__ gcand) {
    const int b = blockIdx.x / NCH2;
    const int ch = blockIdx.x % NCH2;
    const int p0 = ch * 256;
    const int n = min(256, P_ - p0);          // 256 or 28; always %4 == 0
    const int tid = threadIdx.x;
    __shared__ float tile[256 * C_];
    const float4* src4 = (const float4*)(conf + ((size_t)b * P_ + p0) * C_);
    float4* tile4 = (float4*)tile;
    const int tot4 = (n * C_) >> 2;
    for (int i = tid; i < tot4; i += 256) tile4[i] = src4[i];
    __syncthreads();
    const uint32_t T0 = thr0();
    const int pg = tid & 63;                  // 4-prior group
    const int cs = tid >> 6;                  // class slice 0..3
    const int ng = n >> 2;                    // 64 or 7
    if (pg < ng) {
        for (int c = (cs == 0 ? 4 : cs); c < C_; c += 4) {   // class 0 output is zeroed: skip
            const float* tp = &tile[4 * pg * C_ + c];
            uint32_t kk0 = keyof(tp[0 * C_]);
            uint32_t kk1 = keyof(tp[1 * C_]);
            uint32_t kk2 = keyof(tp[2 * C_]);
            uint32_t kk3 = keyof(tp[3 * C_]);
            int nq = (kk0 >= T0) + (kk1 >= T0) + (kk2 >= T0) + (kk3 >= T0);
            if (nq) {
                uint32_t pos = atomicAdd(&gcnt[b * C_ + c], (uint32_t)nq);
                uint64_t* dst = gcand + (size_t)(b * C_ + c) * CAP;
                const int pb = p0 + 4 * pg;
                uint32_t kk[4] = {kk0, kk1, kk2, kk3};
                #pragma unroll
                for (int k = 0; k < 4; ++k) {
                    if (kk[k] >= T0) {
                        if (pos < CAP)
                            dst[pos] = ((uint64_t)kk[k] << 32) | (uint32_t)(~(uint32_t)(pb + k));
                        ++pos;
                    }
                }
            }
        }
    }
}

template<bool HASWS>
__global__ __launch_bounds__(NT, 6) void detect_kernel(
    const float* __restrict__ loc, const float* __restrict__ prior,
    const uint32_t* __restrict__ gcnt, const uint64_t* __restrict__ gcand,
    const float* __restrict__ conf, float* __restrict__ out)
{
    const int task = blockIdx.x;
    const int b = task / C_;
    const int c = task % C_;
    const int tid = threadIdx.x;
    const int lane = tid & 63;
    float* outp = out + (size_t)task * TOPK * 5;

    if (c == 0) {  // out.at[:,0].set(0.0)
        for (int e = tid; e < TOPK * 5; e += NT) outp[e] = 0.0f;
        return;
    }

    __shared__ uint64_t cand[256];
    __shared__ float4 bbox[TOPK];
    __shared__ float bs[TOPK];
    __shared__ unsigned long long msk[TOPK * 4];
    __shared__ unsigned long long vmask[4];
    __shared__ int order[TOPK];
    __shared__ int s_cnt, s_nk;
    __shared__ int s_c2[2];

    const uint32_t T0 = thr0();
    int gc = 0;
    if (HASWS) gc = (int)gcnt[task];
    const bool fast = HASWS && gc >= TOPK && gc <= CAP;   // ~always (window is +-5.9 sigma)

    // ---- one-time zeroing ----
    if (tid == 0) s_cnt = 0;
    if (tid < 2) s_c2[tid] = 0;
    for (int i2 = tid; i2 < TOPK * 4; i2 += NT) msk[i2] = 0ull;

    uint64_t vcand = 0;            // fast path: one candidate per thread
    uint4 kv[KV4];                 // slow path: strided keys
    if (fast) {
        if (tid < gc) vcand = gcand[(size_t)task * CAP + tid];
    } else {
        const float* sp = conf + (size_t)b * P_ * C_ + c;
        #pragma unroll
        for (int r = 0; r < KV4; ++r) {
            uint32_t uu[4];
            #pragma unroll
            for (int c4 = 0; c4 < 4; ++c4) {
                int p = (tid + r * NT) * 4 + c4;
                if (p < P_) {
                    float v = sp[(size_t)p * C_];
                    v = (v > CONF_T) ? v : -1.0f;
                    uu[c4] = f2s(v);
                } else uu[c4] = 0u;
            }
            kv[r] = make_uint4(uu[0], uu[1], uu[2], uu[3]);
        }
    }
    __syncthreads();

    // ---- threshold with count in [200,256], then compact ----
    if (fast) {
        uint32_t vthr = T0;
        if (gc > 256) {   // raise threshold within the candidate set (1 key/thread)
            uint32_t lo = T0, hi = 0xFFFFFFFFu;
            const uint32_t myk = (uint32_t)(vcand >> 32);
            uint32_t t;
            {
                const float sc = s2f(T0);
                const float sn = 1.0f - (1.0f - sc) * (float)TGT / (float)gc;
                t = f2s(sn);
                if (!(t > lo && t < hi)) t = lo + ((hi - lo) >> 1);
            }
            for (int it = 0; ; ++it) {
                const int slot = it & 1;
                int my = (tid < gc && myk >= t) ? 1 : 0;
                #pragma unroll
                for (int d = 1; d < 64; d <<= 1) my += __shfl_down(my, d);
                if (lane == 0) atomicAdd(&s_c2[slot], my);
                __syncthreads();
                const int cnt = s_c2[slot];
                __syncthreads();
                if (tid == 0) s_c2[slot] = 0;
                if (cnt >= TOPK && cnt <= 256) { vthr = t; break; }
                if (cnt > 256) lo = t; else hi = t;
                if (hi - lo <= 1) { vthr = lo; break; }
                uint32_t tn = 0;
                bool bis = (it >= 8) || (cnt == 0);
                if (!bis) {
                    const float sc = s2f(t);
                    const float sn = 1.0f - (1.0f - sc) * (float)TGT / (float)cnt;
                    tn = f2s(sn);
                    if (!(tn > lo && tn < hi)) bis = true;
                }
                if (bis) tn = lo + ((hi - lo) >> 1);
                t = tn;
            }
        }
        if (tid < gc && (uint32_t)(vcand >> 32) >= vthr) {
            int pos = atomicAdd(&s_cnt, 1);
            if (pos < 256) cand[pos] = vcand;
        }
    } else {
        // full interpolated count-search over strided keys (rare / no-ws path)
        uint32_t lo = 0u, hi = 0xFFFFFFFFu;
        uint32_t t = f2s(1.0f - (float)TGT / (float)P_);
        uint32_t vthr = 0u;
        for (int it = 0; ; ++it) {
            const int slot = it & 1;
            int my = 0;
            #pragma unroll
            for (int r = 0; r < KV4; ++r)
                my += (kv[r].x >= t) + (kv[r].y >= t) + (kv[r].z >= t) + (kv[r].w >= t);
            #pragma unroll
            for (int d = 1; d < 64; d <<= 1) my += __shfl_down(my, d);
            if (lane == 0) atomicAdd(&s_c2[slot], my);
            __syncthreads();
            const int cnt = s_c2[slot];
            __syncthreads();
            if (tid == 0) s_c2[slot] = 0;
            if (cnt >= TOPK && cnt <= 256) { vthr = t; break; }
            if (cnt > 256) lo = t; else hi = t;
            if (hi - lo <= 1) { vthr = lo; break; }
            uint32_t tn = 0;
            bool bis = (it >= 8) || (cnt == 0);
            if (!bis) {
                const float sc = s2f(t);
                const float sn = 1.0f - (1.0f - sc) * (float)TGT / (float)cnt;
                tn = f2s(sn);
                if (!(tn > lo && tn < hi)) bis = true;
            }
            if (bis) tn = lo + ((hi - lo) >> 1);
            t = tn;
        }
        #pragma unroll
        for (int r = 0; r < KV4; ++r) {
            const int pb = (tid + r * NT) * 4;
            uint32_t uu[4] = {kv[r].x, kv[r].y, kv[r].z, kv[r].w};
            #pragma unroll
            for (int c4 = 0; c4 < 4; ++c4) {
                uint32_t u = uu[c4];
                if (u >= vthr) {
                    int pos = atomicAdd(&s_cnt, 1);
                    if (pos < 256) cand[pos] = ((uint64_t)u << 32) | (uint32_t)(~(uint32_t)(pb + c4));
                }
            }
        }
    }
    __syncthreads();
    if (tid < 256 && tid >= s_cnt) cand[tid] = 0ull;   // pad sorts to the end
    __syncthreads();

    // ---- bitonic sort 256 keys desc (val desc, idx asc) == jax.lax.top_k ----
    uint64_t v = (tid < 256) ? cand[tid] : 0ull;
    for (int kk = 2; kk <= 256; kk <<= 1) {
        for (int j = kk >> 1; j > 0; j >>= 1) {
            if (j >= 64) {
                __syncthreads();
                if (tid < 256) cand[tid] = v;
                __syncthreads();
                if (tid < 256) {
                    uint64_t pv = cand[tid ^ j];
                    bool keepmax = (((tid & j) == 0) == ((tid & kk) == 0));
                    v = keepmax ? (v > pv ? v : pv) : (v < pv ? v : pv);
                }
            } else if (tid < 256) {
                uint64_t pv = __shfl_xor(v, j);
                bool keepmax = (((tid & j) == 0) == ((tid & kk) == 0));
                v = keepmax ? (v > pv ? v : pv) : (v < pv ? v : pv);
            }
        }
    }

    // ---- decode top-200 boxes (exact ref f32 op order, no contraction) ----
    float my_sc = -1.0f;
    if (tid < TOPK) {
        uint32_t su = (uint32_t)(v >> 32);
        int p = (int)(~(uint32_t)v);
        my_sc = s2f(su);
        const float4 l4 = *(const float4*)(loc + ((size_t)b * P_ + p) * 4);
        const float4 pr = *(const float4*)(prior + (size_t)p * 4);
        float cx = __fadd_rn(pr.x, __fmul_rn(__fmul_rn(l4.x, 0.1f), pr.z));
        float cy = __fadd_rn(pr.y, __fmul_rn(__fmul_rn(l4.y, 0.1f), pr.w));
        float ew = (float)exp((double)__fmul_rn(l4.z, 0.2f));
        float eh = (float)exp((double)__fmul_rn(l4.w, 0.2f));
        float w  = __fmul_rn(pr.z, ew);
        float h  = __fmul_rn(pr.w, eh);
        float x1 = __fsub_rn(cx, __fmul_rn(w, 0.5f));
        float y1 = __fsub_rn(cy, __fmul_rn(h, 0.5f));
        float x2 = __fadd_rn(x1, w);
        float y2 = __fadd_rn(y1, h);
        bs[tid] = my_sc;
        bbox[tid] = make_float4(x1, y1, x2, y2);
    }
    {
        unsigned long long bm = __ballot(tid < TOPK && my_sc > CONF_T);
        if (lane == 0 && tid < 256) vmask[tid >> 6] = bm;
    }
    __syncthreads();

    // ---- pairwise IoU: balanced row-pairing; areas recomputed inline ----
    if (tid < 500) {
        const int rp = tid / 5;        // row-pair id in [0,100)
        const int s  = tid - rp * 5;   // sub-lane in [0,5)
        #pragma unroll
        for (int pass = 0; pass < 2; ++pass) {
            const int j  = pass ? (199 - rp) : rp;
            const int i0 = j + 1 + s;
            const float4 bj = bbox[j];
            const float  aj = __fmul_rn(__fsub_rn(bj.z, bj.x), __fsub_rn(bj.w, bj.y));
            for (int i = i0; i < TOPK; i += 5) {
                const float4 bi = bbox[i];
                float xx1 = fmaxf(bj.x, bi.x);
                float yy1 = fmaxf(bj.y, bi.y);
                float xx2 = fminf(bj.z, bi.z);
                float yy2 = fminf(bj.w, bi.w);
                float dx = fmaxf(__fsub_rn(xx2, xx1), 0.0f);
                float dy = fmaxf(__fsub_rn(yy2, yy1), 0.0f);
                float inter = __fmul_rn(dx, dy);
                if (inter > 0.0f) {
                    float ai = __fmul_rn(__fsub_rn(bi.z, bi.x), __fsub_rn(bi.w, bi.y));
                    float uni = __fsub_rn(__fadd_rn(aj, ai), inter);
                    float t45 = __fmul_rn(NMS_T, uni);
                    float mar = __fmul_rn(t45, 1e-6f);
                    bool sup;
                    if (inter > __fadd_rn(t45, mar)) sup = true;
                    else if (inter < __fsub_rn(t45, mar)) sup = false;
                    else sup = (inter / uni > NMS_T);   // exact IEEE path, tie band only
                    if (sup) atomicOr(&msk[j * 4 + (i >> 6)], 1ull << (i & 63));
                }
            }
        }
    }
    __syncthreads();

    // ---- greedy NMS: word-blocked wave-0 scan (1 shfl/pick, deferred cross-word OR) ----
    if (tid < 64) {
        const int L = tid;
        auto or_reduce = [&](unsigned long long x) {
            #pragma unroll
            for (int d = 1; d < 64; d <<= 1) x |= __shfl_xor(x, d);
            return x;
        };
        unsigned long long s1 = 0, s2 = 0, s3 = 0;   // incoming suppression, words 1..3
        int nk = 0;
        #pragma unroll
        for (int w = 0; w < 4; ++w) {
            const int j = (w << 6) | L;
            unsigned long long r0 = 0, r1 = 0, r2 = 0, r3 = 0;
            if (j < TOPK) {
                const unsigned long long* mr = &msk[j * 4];
                r0 = mr[0]; r1 = mr[1]; r2 = mr[2]; r3 = mr[3];
            }
            const unsigned long long rself = (w == 0) ? r0 : (w == 1) ? r1
                                           : (w == 2) ? r2 : r3;
            unsigned long long sw = (w == 0) ? 0ull : (w == 1) ? s1
                                  : (w == 2) ? s2 : s3;
            unsigned long long alive = vmask[w] & ~sw;
            unsigned long long pm = 0;
            while (alive) {
                int jl = __ffsll(alive) - 1;
                if (L == 0) order[nk] = (w << 6) | jl;
                ++nk;
                sw |= __shfl(rself, jl);             // suppression within this word
                pm |= (1ull << jl);
                alive &= ~(sw | (1ull << jl));
            }
            if (pm) {   // deferred: OR picked rows' later-word masks (mask bits are i>j only)
                const bool picked = (pm >> L) & 1ull;
                if (w == 0) {
                    s1 |= or_reduce(picked ? r1 : 0ull);
                    s2 |= or_reduce(picked ? r2 : 0ull);
                    s3 |= or_reduce(picked ? r3 : 0ull);
                } else if (w == 1) {
                    s2 |= or_reduce(picked ? r2 : 0ull);
                    s3 |= or_reduce(picked ? r3 : 0ull);
                } else if (w == 2) {
                    s3 |= or_reduce(picked ? r3 : 0ull);
                }
            }
        }
        if (L == 0) s_nk = nk;
    }
    __syncthreads();

    // ---- compacted output ----
    const int nk = s_nk;
    for (int e = tid; e < TOPK * 5; e += NT) {
        int r = e / 5;
        int f = e - r * 5;
        float val = 0.0f;
        if (r < nk) {
            int j = order[r];
            float4 bb = bbox[j];
            val = (f == 0) ? bs[j] : (f == 1) ? bb.x : (f == 2) ? bb.y
                : (f == 3) ? bb.z : bb.w;
        }
        outp[e] = val;
    }
}

extern "C" void kernel_launch(void* const* d_in, const int* in_sizes, int n_in,
                              void* d_out, int out_size, void* d_ws, size_t ws_size,
                              hipStream_t stream) {
    const float* loc   = (const float*)d_in[0];
    const float* conf  = (const float*)d_in[1];
    const float* prior = (const float*)d_in[2];
    float* out = (float*)d_out;

    const size_t cnt_bytes  = 4096;                             // NTASK u32, padded
    const size_t cand_bytes = (size_t)NTASK * CAP * sizeof(uint64_t);
    if (ws_size >= cnt_bytes + cand_bytes) {
        uint32_t* gcnt  = (uint32_t*)d_ws;
        uint64_t* gcand = (uint64_t*)((char*)d_ws + cnt_bytes);
        hipMemsetAsync(gcnt, 0, (size_t)NTASK * sizeof(uint32_t), stream);
        scatter_cands<<<B_ * NCH2, 256, 0, stream>>>(conf, gcnt, gcand);
        detect_kernel<true><<<NTASK, NT, 0, stream>>>(loc, prior, gcnt, gcand, conf, out);
    } else {
        detect_kernel<false><<<NTASK, NT, 0, stream>>>(loc, prior, nullptr, nullptr, conf, out);
    }
}

// Round 13
// 123.336 us; speedup vs baseline: 1.7083x; 1.7083x over previous
//
#include <hip/hip_runtime.h>
#include <stdint.h>

#define B_ 32
#define P_ 8732
#define C_ 21
#define TOPK 200
#define TGT 228        // count-search acceptance window center [200,256]
#define TGT0 300       // scatter pre-filter target count (mean; sigma~17)
#define SUBCAP 28      // per-(task,chunk) slot capacity; Poisson(8.8) P(>28)~1e-7
#define NCH2 35        // ceil(P_/256) chunks
#define NSLOT (NCH2 * SUBCAP)   // 980 slots/task
#define CONF_T 0.01f
#define NMS_T 0.45f
#define NT 512         // 8-wave blocks: the only shape that packs (R5/R7/R10 evidence)
#define KV4 5          // slow-path strided load: ceil((P_/4)/NT)
#define NTASK (B_ * C_)

__device__ __forceinline__ uint32_t f2s(float f) {
    uint32_t u = __float_as_uint(f);
    return (u & 0x80000000u) ? ~u : (u | 0x80000000u);
}
__device__ __forceinline__ float s2f(uint32_t s) {
    uint32_t b = (s & 0x80000000u) ? (s & 0x7FFFFFFFu) : ~s;
    return __uint_as_float(b);
}
__device__ __forceinline__ uint32_t keyof(float v) {
    return f2s((v > CONF_T) ? v : -1.0f);
}
__device__ __forceinline__ uint32_t thr0() {
    return f2s(1.0f - (float)TGT0 / (float)P_);   // folds to a constant
}

// conf (B,P,C) -> chunked per-task candidate lists, NO atomics anywhere:
// wave-level shfl prefix-sum assigns slots; per-chunk counts stored for overflow check.
__global__ __launch_bounds__(256) void scatter_cands(const float* __restrict__ conf,
                                                     uint32_t* __restrict__ gccnt,
                                                     uint64_t* __restrict__ gcand) {
    const int b = blockIdx.x / NCH2;
    const int ch = blockIdx.x % NCH2;
    const int p0 = ch * 256;
    const int n = min(256, P_ - p0);          // 256 or 28; always %4 == 0
    const int tid = threadIdx.x;
    const int lane = tid & 63;
    const int cs = tid >> 6;                  // wave id = class slice 0..3
    __shared__ float tile[256 * C_];
    const float4* src4 = (const float4*)(conf + ((size_t)b * P_ + p0) * C_);
    float4* tile4 = (float4*)tile;
    const int tot4 = (n * C_) >> 2;
    for (int i = tid; i < tot4; i += 256) tile4[i] = src4[i];
    __syncthreads();
    const uint32_t T0 = thr0();
    const bool act = (4 * lane) < n;
    for (int c = (cs == 0 ? 4 : cs); c < C_; c += 4) {   // class 0 output is zeroed: skip
        uint32_t kk[4];
        int nq = 0;
        if (act) {
            const float* tp = &tile[4 * lane * C_ + c];
            kk[0] = keyof(tp[0 * C_]);
            kk[1] = keyof(tp[1 * C_]);
            kk[2] = keyof(tp[2 * C_]);
            kk[3] = keyof(tp[3 * C_]);
            nq = (kk[0] >= T0) + (kk[1] >= T0) + (kk[2] >= T0) + (kk[3] >= T0);
        }
        int incl = nq;                         // wave inclusive prefix-sum
        #pragma unroll
        for (int d = 1; d < 64; d <<= 1) {
            int v = __shfl_up(incl, d);
            if (lane >= d) incl += v;
        }
        const int excl = incl - nq;
        const int total = __shfl(incl, 63);
        const int task = b * C_ + c;
        uint64_t* dst = gcand + ((size_t)task * NCH2 + ch) * SUBCAP;
        if (nq) {
            int pos = excl;
            const int pb = p0 + 4 * lane;
            #pragma unroll
            for (int k = 0; k < 4; ++k) {
                if (kk[k] >= T0) {
                    if (pos < SUBCAP)
                        dst[pos] = ((uint64_t)kk[k] << 32) | (uint32_t)(~(uint32_t)(pb + k));
                    ++pos;
                }
            }
        }
        if (lane == 0) gccnt[(size_t)task * NCH2 + ch] = (uint32_t)total;
    }
}

template<bool HASWS>
__global__ __launch_bounds__(NT, 6) void detect_kernel(
    const float* __restrict__ loc, const float* __restrict__ prior,
    const uint32_t* __restrict__ gccnt, const uint64_t* __restrict__ gcand,
    const float* __restrict__ conf, float* __restrict__ out)
{
    const int task = blockIdx.x;
    const int b = task / C_;
    const int c = task % C_;
    const int tid = threadIdx.x;
    const int lane = tid & 63;
    float* outp = out + (size_t)task * TOPK * 5;

    if (c == 0) {  // out.at[:,0].set(0.0)
        for (int e = tid; e < TOPK * 5; e += NT) outp[e] = 0.0f;
        return;
    }

    __shared__ uint64_t cand[256];
    __shared__ float4 bbox[TOPK];
    __shared__ float bs[TOPK];
    __shared__ unsigned long long msk[TOPK * 4];
    __shared__ unsigned long long vmask[4];
    __shared__ int order[TOPK];
    __shared__ int s_cnt, s_nk;
    __shared__ int s_c2[2];
    __shared__ uint32_t s_ccnt[NCH2];
    __shared__ int s_gc, s_bad;

    const uint32_t T0 = thr0();

    // ---- one-time zeroing + chunk-count load ----
    if (tid == 0) s_cnt = 0;
    if (tid < 2) s_c2[tid] = 0;
    if (HASWS && tid < NCH2) s_ccnt[tid] = gccnt[(size_t)task * NCH2 + tid];
    for (int i2 = tid; i2 < TOPK * 4; i2 += NT) msk[i2] = 0ull;
    __syncthreads();
    if (HASWS && tid < 64) {           // wave 0: total + overflow check
        uint32_t cc = (lane < NCH2) ? s_ccnt[lane] : 0u;
        int bad = (cc > SUBCAP) ? 1 : 0;
        int tot = (int)cc;
        #pragma unroll
        for (int d = 1; d < 64; d <<= 1) {
            tot += __shfl_down(tot, d);
            bad |= __shfl_down(bad, d);
        }
        if (lane == 0) { s_gc = tot; s_bad = bad; }
    }
    __syncthreads();

    const bool fast = HASWS && !s_bad && s_gc >= TOPK;   // ~always
    const int gc = HASWS ? s_gc : 0;

    uint64_t vc0 = 0, vc1 = 0;         // fast path: <=2 candidates per thread
    bool val0 = false, val1 = false;
    uint4 kv[KV4];                     // slow path: strided keys
    if (fast) {
        const uint64_t* gp = gcand + (size_t)task * NSLOT;
        {
            const int ch0 = tid / SUBCAP, i0 = tid - ch0 * SUBCAP;
            if (i0 < (int)s_ccnt[ch0]) { vc0 = gp[tid]; val0 = true; }
        }
        const int s1 = tid + NT;
        if (s1 < NSLOT) {
            const int ch1 = s1 / SUBCAP, i1 = s1 - ch1 * SUBCAP;
            if (i1 < (int)s_ccnt[ch1]) { vc1 = gp[s1]; val1 = true; }
        }
    } else {
        const float* sp = conf + (size_t)b * P_ * C_ + c;
        #pragma unroll
        for (int r = 0; r < KV4; ++r) {
            uint32_t uu[4];
            #pragma unroll
            for (int c4 = 0; c4 < 4; ++c4) {
                int p = (tid + r * NT) * 4 + c4;
                if (p < P_) {
                    float v = sp[(size_t)p * C_];
                    v = (v > CONF_T) ? v : -1.0f;
                    uu[c4] = f2s(v);
                } else uu[c4] = 0u;
            }
            kv[r] = make_uint4(uu[0], uu[1], uu[2], uu[3]);
        }
    }

    // ---- threshold with count in [200,256], then compact ----
    if (fast) {
        uint32_t vthr = T0;
        if (gc > 256) {   // raise threshold within candidates (<=2 keys/thread)
            const uint32_t k0 = (uint32_t)(vc0 >> 32);
            const uint32_t k1 = (uint32_t)(vc1 >> 32);
            uint32_t lo = T0, hi = 0xFFFFFFFFu;
            uint32_t t;
            {
                const float sc = s2f(T0);
                const float sn = 1.0f - (1.0f - sc) * (float)TGT / (float)gc;
                t = f2s(sn);
                if (!(t > lo && t < hi)) t = lo + ((hi - lo) >> 1);
            }
            for (int it = 0; ; ++it) {
                const int slot = it & 1;
                int my = (val0 && k0 >= t) + (val1 && k1 >= t);
                #pragma unroll
                for (int d = 1; d < 64; d <<= 1) my += __shfl_down(my, d);
                if (lane == 0) atomicAdd(&s_c2[slot], my);
                __syncthreads();
                const int cnt = s_c2[slot];
                __syncthreads();
                if (tid == 0) s_c2[slot] = 0;
                if (cnt >= TOPK && cnt <= 256) { vthr = t; break; }
                if (cnt > 256) lo = t; else hi = t;
                if (hi - lo <= 1) { vthr = lo; break; }
                uint32_t tn = 0;
                bool bis = (it >= 8) || (cnt == 0);
                if (!bis) {
                    const float sc = s2f(t);
                    const float sn = 1.0f - (1.0f - sc) * (float)TGT / (float)cnt;
                    tn = f2s(sn);
                    if (!(tn > lo && tn < hi)) bis = true;
                }
                if (bis) tn = lo + ((hi - lo) >> 1);
                t = tn;
            }
        }
        if (val0 && (uint32_t)(vc0 >> 32) >= vthr) {
            int pos = atomicAdd(&s_cnt, 1);
            if (pos < 256) cand[pos] = vc0;
        }
        if (val1 && (uint32_t)(vc1 >> 32) >= vthr) {
            int pos = atomicAdd(&s_cnt, 1);
            if (pos < 256) cand[pos] = vc1;
        }
    } else {
        // full interpolated count-search over strided keys (rare / no-ws path)
        uint32_t lo = 0u, hi = 0xFFFFFFFFu;
        uint32_t t = f2s(1.0f - (float)TGT / (float)P_);
        uint32_t vthr = 0u;
        for (int it = 0; ; ++it) {
            const int slot = it & 1;
            int my = 0;
            #pragma unroll
            for (int r = 0; r < KV4; ++r)
                my += (kv[r].x >= t) + (kv[r].y >= t) + (kv[r].z >= t) + (kv[r].w >= t);
            #pragma unroll
            for (int d = 1; d < 64; d <<= 1) my += __shfl_down(my, d);
            if (lane == 0) atomicAdd(&s_c2[slot], my);
            __syncthreads();
            const int cnt = s_c2[slot];
            __syncthreads();
            if (tid == 0) s_c2[slot] = 0;
            if (cnt >= TOPK && cnt <= 256) { vthr = t; break; }
            if (cnt > 256) lo = t; else hi = t;
            if (hi - lo <= 1) { vthr = lo; break; }
            uint32_t tn = 0;
            bool bis = (it >= 8) || (cnt == 0);
            if (!bis) {
                const float sc = s2f(t);
                const float sn = 1.0f - (1.0f - sc) * (float)TGT / (float)cnt;
                tn = f2s(sn);
                if (!(tn > lo && tn < hi)) bis = true;
            }
            if (bis) tn = lo + ((hi - lo) >> 1);
            t = tn;
        }
        #pragma unroll
        for (int r = 0; r < KV4; ++r) {
            const int pb = (tid + r * NT) * 4;
            uint32_t uu[4] = {kv[r].x, kv[r].y, kv[r].z, kv[r].w};
            #pragma unroll
            for (int c4 = 0; c4 < 4; ++c4) {
                uint32_t u = uu[c4];
                if (u >= vthr) {
                    int pos = atomicAdd(&s_cnt, 1);
                    if (pos < 256) cand[pos] = ((uint64_t)u << 32) | (uint32_t)(~(uint32_t)(pb + c4));
                }
            }
        }
    }
    __syncthreads();
    if (tid < 256 && tid >= s_cnt) cand[tid] = 0ull;   // pad sorts to the end
    __syncthreads();

    // ---- bitonic sort 256 keys desc (val desc, idx asc) == jax.lax.top_k ----
    uint64_t v = (tid < 256) ? cand[tid] : 0ull;
    for (int kk = 2; kk <= 256; kk <<= 1) {
        for (int j = kk >> 1; j > 0; j >>= 1) {
            if (j >= 64) {
                __syncthreads();
                if (tid < 256) cand[tid] = v;
                __syncthreads();
                if (tid < 256) {
                    uint64_t pv = cand[tid ^ j];
                    bool keepmax = (((tid & j) == 0) == ((tid & kk) == 0));
                    v = keepmax ? (v > pv ? v : pv) : (v < pv ? v : pv);
                }
            } else if (tid < 256) {
                uint64_t pv = __shfl_xor(v, j);
                bool keepmax = (((tid & j) == 0) == ((tid & kk) == 0));
                v = keepmax ? (v > pv ? v : pv) : (v < pv ? v : pv);
            }
        }
    }

    // ---- decode top-200 boxes (exact ref f32 op order, no contraction) ----
    float my_sc = -1.0f;
    if (tid < TOPK) {
        uint32_t su = (uint32_t)(v >> 32);
        int p = (int)(~(uint32_t)v);
        my_sc = s2f(su);
        const float4 l4 = *(const float4*)(loc + ((size_t)b * P_ + p) * 4);
        const float4 pr = *(const float4*)(prior + (size_t)p * 4);
        float cx = __fadd_rn(pr.x, __fmul_rn(__fmul_rn(l4.x, 0.1f), pr.z));
        float cy = __fadd_rn(pr.y, __fmul_rn(__fmul_rn(l4.y, 0.1f), pr.w));
        float ew = (float)exp((double)__fmul_rn(l4.z, 0.2f));
        float eh = (float)exp((double)__fmul_rn(l4.w, 0.2f));
        float w  = __fmul_rn(pr.z, ew);
        float h  = __fmul_rn(pr.w, eh);
        float x1 = __fsub_rn(cx, __fmul_rn(w, 0.5f));
        float y1 = __fsub_rn(cy, __fmul_rn(h, 0.5f));
        float x2 = __fadd_rn(x1, w);
        float y2 = __fadd_rn(y1, h);
        bs[tid] = my_sc;
        bbox[tid] = make_float4(x1, y1, x2, y2);
    }
    {
        unsigned long long bm = __ballot(tid < TOPK && my_sc > CONF_T);
        if (lane == 0 && tid < 256) vmask[tid >> 6] = bm;
    }
    __syncthreads();

    // ---- pairwise IoU: balanced row-pairing; areas recomputed inline ----
    if (tid < 500) {
        const int rp = tid / 5;        // row-pair id in [0,100)
        const int s  = tid - rp * 5;   // sub-lane in [0,5)
        #pragma unroll
        for (int pass = 0; pass < 2; ++pass) {
            const int j  = pass ? (199 - rp) : rp;
            const int i0 = j + 1 + s;
            const float4 bj = bbox[j];
            const float  aj = __fmul_rn(__fsub_rn(bj.z, bj.x), __fsub_rn(bj.w, bj.y));
            for (int i = i0; i < TOPK; i += 5) {
                const float4 bi = bbox[i];
                float xx1 = fmaxf(bj.x, bi.x);
                float yy1 = fmaxf(bj.y, bi.y);
                float xx2 = fminf(bj.z, bi.z);
                float yy2 = fminf(bj.w, bi.w);
                float dx = fmaxf(__fsub_rn(xx2, xx1), 0.0f);
                float dy = fmaxf(__fsub_rn(yy2, yy1), 0.0f);
                float inter = __fmul_rn(dx, dy);
                if (inter > 0.0f) {
                    float ai = __fmul_rn(__fsub_rn(bi.z, bi.x), __fsub_rn(bi.w, bi.y));
                    float uni = __fsub_rn(__fadd_rn(aj, ai), inter);
                    float t45 = __fmul_rn(NMS_T, uni);
                    float mar = __fmul_rn(t45, 1e-6f);
                    bool sup;
                    if (inter > __fadd_rn(t45, mar)) sup = true;
                    else if (inter < __fsub_rn(t45, mar)) sup = false;
                    else sup = (inter / uni > NMS_T);   // exact IEEE path, tie band only
                    if (sup) atomicOr(&msk[j * 4 + (i >> 6)], 1ull << (i & 63));
                }
            }
        }
    }
    __syncthreads();

    // ---- greedy NMS: word-blocked wave-0 scan (1 shfl/pick, deferred cross-word OR) ----
    if (tid < 64) {
        const int L = tid;
        auto or_reduce = [&](unsigned long long x) {
            #pragma unroll
            for (int d = 1; d < 64; d <<= 1) x |= __shfl_xor(x, d);
            return x;
        };
        unsigned long long s1 = 0, s2 = 0, s3 = 0;   // incoming suppression, words 1..3
        int nk = 0;
        #pragma unroll
        for (int w = 0; w < 4; ++w) {
            const int j = (w << 6) | L;
            unsigned long long r0 = 0, r1 = 0, r2 = 0, r3 = 0;
            if (j < TOPK) {
                const unsigned long long* mr = &msk[j * 4];
                r0 = mr[0]; r1 = mr[1]; r2 = mr[2]; r3 = mr[3];
            }
            const unsigned long long rself = (w == 0) ? r0 : (w == 1) ? r1
                                           : (w == 2) ? r2 : r3;
            unsigned long long sw = (w == 0) ? 0ull : (w == 1) ? s1
                                  : (w == 2) ? s2 : s3;
            unsigned long long alive = vmask[w] & ~sw;
            unsigned long long pm = 0;
            while (alive) {
                int jl = __ffsll(alive) - 1;
                if (L == 0) order[nk] = (w << 6) | jl;
                ++nk;
                sw |= __shfl(rself, jl);             // suppression within this word
                pm |= (1ull << jl);
                alive &= ~(sw | (1ull << jl));
            }
            if (pm) {   // deferred: OR picked rows' later-word masks (mask bits are i>j only)
                const bool picked = (pm >> L) & 1ull;
                if (w == 0) {
                    s1 |= or_reduce(picked ? r1 : 0ull);
                    s2 |= or_reduce(picked ? r2 : 0ull);
                    s3 |= or_reduce(picked ? r3 : 0ull);
                } else if (w == 1) {
                    s2 |= or_reduce(picked ? r2 : 0ull);
                    s3 |= or_reduce(picked ? r3 : 0ull);
                } else if (w == 2) {
                    s3 |= or_reduce(picked ? r3 : 0ull);
                }
            }
        }
        if (L == 0) s_nk = nk;
    }
    __syncthreads();

    // ---- compacted output ----
    const int nk = s_nk;
    for (int e = tid; e < TOPK * 5; e += NT) {
        int r = e / 5;
        int f = e - r * 5;
        float val = 0.0f;
        if (r < nk) {
            int j = order[r];
            float4 bb = bbox[j];
            val = (f == 0) ? bs[j] : (f == 1) ? bb.x : (f == 2) ? bb.y
                : (f == 3) ? bb.z : bb.w;
        }
        outp[e] = val;
    }
}

extern "C" void kernel_launch(void* const* d_in, const int* in_sizes, int n_in,
                              void* d_out, int out_size, void* d_ws, size_t ws_size,
                              hipStream_t stream) {
    const float* loc   = (const float*)d_in[0];
    const float* conf  = (const float*)d_in[1];
    const float* prior = (const float*)d_in[2];
    float* out = (float*)d_out;

    const size_t cnt_bytes  = (size_t)NTASK * NCH2 * sizeof(uint32_t);   // 94,080 (8-aligned)
    const size_t cand_bytes = (size_t)NTASK * NSLOT * sizeof(uint64_t);  // ~5.3 MB
    if (ws_size >= cnt_bytes + cand_bytes) {
        uint32_t* gccnt = (uint32_t*)d_ws;
        uint64_t* gcand = (uint64_t*)((char*)d_ws + cnt_bytes);
        scatter_cands<<<B_ * NCH2, 256, 0, stream>>>(conf, gccnt, gcand);
        detect_kernel<true><<<NTASK, NT, 0, stream>>>(loc, prior, gccnt, gcand, conf, out);
    } else {
        detect_kernel<false><<<NTASK, NT, 0, stream>>>(loc, prior, nullptr, nullptr, conf, out);
    }
}